// Round 10
// baseline (427.104 us; speedup 1.0000x reference)
//
#include <hip/hip_runtime.h>
#include <hip/hip_bf16.h>
#include <math.h>

#define B_  4
#define N_  4096
#define D_  1024
#define H_  16
#define DK_ 64
#define M_  256
#define R_  (B_*N_)          // 16384 rows
#define EPS_ 1e-6f
#define VTROWS_ 80           // 64 V rows + row64=ones(ksum) + 65..79 pad
#define KVROWS_ 128          // KVb bf16: 64 KV + 64=ksum_hi + 65=ksum_lo + 0-pad
#define PHK_PAD 68           // fused_kv  Phi LDS [m][68]  (n-HALF + pad)
#define PHQ_PAD 264          // fused_ctx Phi LDS [n][264]

typedef __bf16 bf16;
typedef __bf16 bf16x4 __attribute__((ext_vector_type(4)));
typedef __bf16 bf16x8 __attribute__((ext_vector_type(8)));
typedef _Float16 f16;
typedef _Float16 f16x4 __attribute__((ext_vector_type(4)));
typedef _Float16 f16x8 __attribute__((ext_vector_type(8)));
typedef float  f32x4  __attribute__((ext_vector_type(4)));

#define GLD(gp, lp) __builtin_amdgcn_global_load_lds( \
    (const __attribute__((address_space(1))) void*)(gp), \
    (__attribute__((address_space(3))) void*)(lp), 16, 0, 0)

#define BAR_()   __builtin_amdgcn_s_barrier()
#define SBAR_()  __builtin_amdgcn_sched_barrier(0)
#define PRIO1_() __builtin_amdgcn_s_setprio(1)
#define PRIO0_() __builtin_amdgcn_s_setprio(0)
#define LGK0_()  do { asm volatile("s_waitcnt lgkmcnt(0)"); SBAR_(); } while (0)
#define LGK8_()  asm volatile("s_waitcnt lgkmcnt(8)")
#define VMC4_()  do { asm volatile("s_waitcnt vmcnt(4)"); SBAR_(); } while (0)

// ---------------------------------------------------------------------------
// prep_all: all 6 elementwise prep ops in ONE launch (range-branched).
// ---------------------------------------------------------------------------
__global__ __launch_bounds__(256)
void prep_all(const float* __restrict__ x, f16* __restrict__ xh,
              const float* __restrict__ Wqkv, f16* __restrict__ Wh,
              const float* __restrict__ omega, f16* __restrict__ omhi,
              f16* __restrict__ omlo,
              const float* __restrict__ Wout, bf16* __restrict__ Wob,
              float* __restrict__ KVt32, bf16* __restrict__ VT)
{
    const int bid = blockIdx.x, tid = threadIdx.x;
    if (bid < 16384) {                       // x -> xh  (f16x4)
        int i = bid*256 + tid;
        float4 v = ((const float4*)x)[i];
        f16x4 h = { (f16)v.x, (f16)v.y, (f16)v.z, (f16)v.w };
        ((f16x4*)xh)[i] = h;
    } else if (bid < 19456) {                // Wqkv -> Wh
        int i = (bid - 16384)*256 + tid;
        float4 v = ((const float4*)Wqkv)[i];
        f16x4 h = { (f16)v.x, (f16)v.y, (f16)v.z, (f16)v.w };
        ((f16x4*)Wh)[i] = h;
    } else if (bid < 19712) {                // omega -> omhi + omlo (residual)
        int i = (bid - 19456)*256 + tid;
        float4 v = ((const float4*)omega)[i];
        f16x4 h = { (f16)v.x, (f16)v.y, (f16)v.z, (f16)v.w };
        ((f16x4*)omhi)[i] = h;
        f16x4 l = { (f16)(v.x - (float)h[0]), (f16)(v.y - (float)h[1]),
                    (f16)(v.z - (float)h[2]), (f16)(v.w - (float)h[3]) };
        ((f16x4*)omlo)[i] = l;
    } else if (bid < 20736) {                // Wout -> Wob (bf16x4)
        int i = (bid - 19712)*256 + tid;
        float4 v = ((const float4*)Wout)[i];
        bf16x4 h = { (bf16)v.x, (bf16)v.y, (bf16)v.z, (bf16)v.w };
        ((bf16x4*)Wob)[i] = h;
    } else if (bid < 22016) {                // zero KVt32 (float4)
        int i = (bid - 20736)*256 + tid;
        ((float4*)KVt32)[i] = make_float4(0.f, 0.f, 0.f, 0.f);
    } else {                                 // VT rows 64..79 (bf16x8)
        int i = (bid - 22016)*256 + tid;     // < 524288
        int bh  = i >> 13;
        int rem = i & 8191;
        int row = 64 + (rem >> 9);
        int n8  = rem & 511;
        bf16 val = (row == 64) ? (bf16)1.0f : (bf16)0.0f;
        bf16x8 pk = { val, val, val, val, val, val, val, val };
        *(bf16x8*)&VT[((size_t)bh*VTROWS_ + row)*N_ + n8*8] = pk;
    }
}

__global__ __launch_bounds__(256)
void pack_kv(const float* __restrict__ KVt32, bf16* __restrict__ KVb)
{
    int i = blockIdx.x * 256 + threadIdx.x;          // 64bh x 128 x 256
    if (i >= B_*H_*KVROWS_*M_) return;
    int bh  = i >> 15;
    int rem = i & 32767;
    int row = rem >> 8;
    int m   = rem & (M_-1);
    bf16 o = (bf16)0.0f;
    if (row < 64) {
        o = (bf16)KVt32[((size_t)bh*VTROWS_ + row)*M_ + m];
    } else if (row == 64) {
        o = (bf16)KVt32[((size_t)bh*VTROWS_ + 64)*M_ + m];
    } else if (row == 65) {
        float v = KVt32[((size_t)bh*VTROWS_ + 64)*M_ + m];
        o = (bf16)(v - (float)(bf16)v);
    }
    KVb[i] = o;
}

// ---------------------------------------------------------------------------
// 8-phase 256x256 GEMM machinery (shared macros).
// ---------------------------------------------------------------------------
#define STAGE_(dstbuf, srcp, kt, half) do { \
    _Pragma("unroll") \
    for (int q_ = 0; q_ < 2; ++q_) { \
        int idx_ = q_*512 + tid; \
        int row_ = idx_ >> 3; \
        int seg_ = (idx_ & 7) ^ (row_ & 7); \
        GLD((srcp) + (size_t)((half)*128 + row_) * D_ + (kt)*64 + seg_*8, \
            &(dstbuf)[(half)*8192 + idx_*8]); \
    } } while (0)

#define LDA_G(T, buf, i0) do { \
    _Pragma("unroll") \
    for (int i_ = 0; i_ < 4; ++i_) { \
        _Pragma("unroll") \
        for (int k_ = 0; k_ < 2; ++k_) { \
            int row_ = warp_m*128 + ((i0)+i_)*16 + m16; \
            int off_ = (row_*128 + k_*64 + quad*16) ^ ((row_ & 7) << 4); \
            a[i_][k_] = *(const T*)((const char*)(buf) + off_); \
        } } } while (0)

#define LDB_G(T, buf, j0) do { \
    _Pragma("unroll") \
    for (int j_ = 0; j_ < 2; ++j_) { \
        _Pragma("unroll") \
        for (int k_ = 0; k_ < 2; ++k_) { \
            int row_ = warp_n*64 + ((j0)+j_)*16 + m16; \
            int off_ = (row_*128 + k_*64 + quad*16) ^ ((row_ & 7) << 4); \
            b[(j0)+j_][k_] = *(const T*)((const char*)(buf) + off_); \
        } } } while (0)

#define MFMA_F16N(I0, J0) do { \
    _Pragma("unroll") \
    for (int i_ = 0; i_ < 4; ++i_) \
        _Pragma("unroll") \
        for (int j_ = 0; j_ < 2; ++j_) \
            _Pragma("unroll") \
            for (int k_ = 0; k_ < 2; ++k_) \
                acc[(I0)+i_][(J0)+j_] = __builtin_amdgcn_mfma_f32_16x16x32_f16( \
                    a[i_][k_], b[(J0)+j_][k_], acc[(I0)+i_][(J0)+j_], 0, 0, 0); \
    } while (0)

#define MFMA_F16S(I0, J0) do { \
    _Pragma("unroll") \
    for (int i_ = 0; i_ < 4; ++i_) \
        _Pragma("unroll") \
        for (int j_ = 0; j_ < 2; ++j_) \
            _Pragma("unroll") \
            for (int k_ = 0; k_ < 2; ++k_) \
                acc[(I0)+i_][(J0)+j_] = __builtin_amdgcn_mfma_f32_16x16x32_f16( \
                    b[(J0)+j_][k_], a[i_][k_], acc[(I0)+i_][(J0)+j_], 0, 0, 0); \
    } while (0)

#define MFMA_BF16S(I0, J0) do { \
    _Pragma("unroll") \
    for (int i_ = 0; i_ < 4; ++i_) \
        _Pragma("unroll") \
        for (int j_ = 0; j_ < 2; ++j_) \
            _Pragma("unroll") \
            for (int k_ = 0; k_ < 2; ++k_) \
                acc[(I0)+i_][(J0)+j_] = __builtin_amdgcn_mfma_f32_16x16x32_bf16( \
                    b[(J0)+j_][k_], a[i_][k_], acc[(I0)+i_][(J0)+j_], 0, 0, 0); \
    } while (0)

#define KLOOP_8PH(MFMA_OP) \
    STAGE_(sA[0], gA, 0, 0); \
    STAGE_(sA[0], gA, 0, 1); \
    STAGE_(sB[0], gB, 0, 0); \
    STAGE_(sB[0], gB, 0, 1); \
    STAGE_(sB[1], gB, 1, 0); \
    STAGE_(sB[1], gB, 1, 1); \
    VMC4_(); \
    BAR_(); \
    for (int it = 0; it < 8; ++it) { \
        const int t1 = 2*it + 1, t2 = 2*it + 2, t3 = 2*it + 3; \
        LDA_G(FRAG_T, sA[0], 0); LDB_G(FRAG_T, sB[0], 0); \
        STAGE_(sA[1], gA, t1, 0); \
        LGK8_(); \
        BAR_(); LGK0_(); \
        PRIO1_(); MFMA_OP(0, 0); PRIO0_(); \
        BAR_(); \
        LDB_G(FRAG_T, sB[0], 2); \
        STAGE_(sA[1], gA, t1, 1); \
        BAR_(); LGK0_(); \
        PRIO1_(); MFMA_OP(0, 2); PRIO0_(); \
        BAR_(); \
        LDA_G(FRAG_T, sA[0], 4); \
        if (t2 < 16) STAGE_(sB[0], gB, t2, 0); \
        BAR_(); LGK0_(); \
        PRIO1_(); MFMA_OP(4, 2); PRIO0_(); \
        BAR_(); \
        if (t2 < 16) STAGE_(sB[0], gB, t2, 1); \
        VMC4_(); \
        BAR_(); \
        PRIO1_(); MFMA_OP(4, 0); PRIO0_(); \
        BAR_(); \
        LDA_G(FRAG_T, sA[1], 0); LDB_G(FRAG_T, sB[1], 0); \
        if (t2 < 16) STAGE_(sA[0], gA, t2, 0); \
        LGK8_(); \
        BAR_(); LGK0_(); \
        PRIO1_(); MFMA_OP(0, 0); PRIO0_(); \
        BAR_(); \
        LDB_G(FRAG_T, sB[1], 2); \
        if (t2 < 16) STAGE_(sA[0], gA, t2, 1); \
        BAR_(); LGK0_(); \
        PRIO1_(); MFMA_OP(0, 2); PRIO0_(); \
        BAR_(); \
        LDA_G(FRAG_T, sA[1], 4); \
        if (t3 < 16) STAGE_(sB[1], gB, t3, 0); \
        BAR_(); LGK0_(); \
        PRIO1_(); MFMA_OP(4, 2); PRIO0_(); \
        BAR_(); \
        if (t3 < 16) STAGE_(sB[1], gB, t3, 1); \
        VMC4_(); \
        BAR_(); \
        PRIO1_(); MFMA_OP(4, 0); PRIO0_(); \
        BAR_(); \
    }

// ---------------------------------------------------------------------------
// Unified QKV projection (unchanged from round 8)
// ---------------------------------------------------------------------------
#define FRAG_T f16x8
__global__ __launch_bounds__(512)
void gemm_qkv_all(const f16* __restrict__ X, const f16* __restrict__ Wh,
                  const float* __restrict__ bqkv,
                  f16* __restrict__ Qh, f16* __restrict__ Kh,
                  bf16* __restrict__ VT)
{
    __shared__ __align__(16) f16 sA[2][256*64];   // 64 KB
    __shared__ __align__(16) f16 sB[2][256*64];   // 64 KB
    const int tid = threadIdx.x;

    const int nwg = gridDim.x * gridDim.y;        // 768 (% 8 == 0)
    int flat = blockIdx.y * gridDim.x + blockIdx.x;
    int wgid = (flat & 7) * (nwg >> 3) + (flat >> 3);
    const int bm  = (wgid / 12) * 256;
    const int bnx = wgid % 12;

    const int lane = tid & 63, wave = tid >> 6;
    const int warp_m = wave >> 2, warp_n = wave & 3;
    const int m16 = lane & 15, quad = lane >> 4;

    f32x4 acc[8][4];
    #pragma unroll
    for (int i = 0; i < 8; ++i)
        #pragma unroll
        for (int j = 0; j < 4; ++j)
            acc[i][j] = (f32x4){0.f, 0.f, 0.f, 0.f};
    f16x8 a[4][2], b[4][2];

    if (bnx < 8) {
        const int bn = bnx * 256;                 // Q (<1024) or K
        const f16* gA = X  + (size_t)bm * D_;
        const f16* gB = Wh + (size_t)bn * D_;

        KLOOP_8PH(MFMA_F16S)

        f16* outp = (bn >= D_) ? Kh : Qh;
        const int cofs = (bn >= D_) ? D_ : 0;
        #pragma unroll
        for (int j = 0; j < 4; ++j) {
            int gcol0 = bn + warp_n*64 + j*16 + quad*4;
            float4 bv = *(const float4*)&bqkv[gcol0];
            int col0 = gcol0 - cofs;
            #pragma unroll
            for (int i = 0; i < 8; ++i) {
                int row = bm + warp_m*128 + i*16 + m16;
                f16x4 pk = { (f16)(acc[i][j][0] + bv.x), (f16)(acc[i][j][1] + bv.y),
                             (f16)(acc[i][j][2] + bv.z), (f16)(acc[i][j][3] + bv.w) };
                *(f16x4*)&outp[(size_t)row * D_ + col0] = pk;
            }
        }
    } else {
        const int bn = 2*D_ + (bnx - 8) * 256;    // V cols
        const f16* gA = X  + (size_t)bm * D_;
        const f16* gB = Wh + (size_t)bn * D_;

        KLOOP_8PH(MFMA_F16N)

        #pragma unroll
        for (int j = 0; j < 4; ++j) {
            int gcol = bn + warp_n*64 + j*16 + m16;
            float bv = bqkv[gcol];
            int vcol = gcol - 2*D_;
            int hh = vcol >> 6, dd = vcol & 63;
            #pragma unroll
            for (int i = 0; i < 8; ++i) {
                int row0 = bm + warp_m*128 + i*16 + quad*4;
                int bb = row0 >> 12, nn = row0 & (N_-1);
                bf16x4 pk = { (bf16)(acc[i][j][0]+bv), (bf16)(acc[i][j][1]+bv),
                              (bf16)(acc[i][j][2]+bv), (bf16)(acc[i][j][3]+bv) };
                *(bf16x4*)&VT[(((size_t)bb*H_+hh)*VTROWS_ + dd)*N_ + nn] = pk;
            }
        }
    }
}
#undef FRAG_T

// ---------------------------------------------------------------------------
// Output projection (unchanged from round 8)
// ---------------------------------------------------------------------------
#define FRAG_T bf16x8
__global__ __launch_bounds__(512)
void gemm_out8(const bf16* __restrict__ A, const bf16* __restrict__ W,
               const float* __restrict__ bias, float* __restrict__ C,
               const int* __restrict__ mask)
{
    __shared__ __align__(16) bf16 sA[2][256*64];
    __shared__ __align__(16) bf16 sB[2][256*64];
    const int tid = threadIdx.x;

    const int nwg = gridDim.x * gridDim.y;        // 256
    int flat = blockIdx.y * gridDim.x + blockIdx.x;
    int wgid = (flat & 7) * (nwg >> 3) + (flat >> 3);
    const int bm = (wgid >> 2) * 256;
    const int bn = (wgid & 3) * 256;

    const int lane = tid & 63, wave = tid >> 6;
    const int warp_m = wave >> 2, warp_n = wave & 3;
    const int m16 = lane & 15, quad = lane >> 4;

    const bf16* gA = A + (size_t)bm * D_;
    const bf16* gB = W + (size_t)bn * D_;

    f32x4 acc[8][4];
    #pragma unroll
    for (int i = 0; i < 8; ++i)
        #pragma unroll
        for (int j = 0; j < 4; ++j)
            acc[i][j] = (f32x4){0.f, 0.f, 0.f, 0.f};
    bf16x8 a[4][2], b[4][2];

    KLOOP_8PH(MFMA_BF16S)

    #pragma unroll
    for (int j = 0; j < 4; ++j) {
        int col0 = bn + warp_n*64 + j*16 + quad*4;
        float4 bv = *(const float4*)&bias[col0];
        #pragma unroll
        for (int i = 0; i < 8; ++i) {
            int row = bm + warp_m*128 + i*16 + m16;
            float4 v;
            if (mask[row] != 0) {
                v = make_float4(0.f, 0.f, 0.f, 0.f);
            } else {
                v = make_float4(acc[i][j][0] + bv.x, acc[i][j][1] + bv.y,
                                acc[i][j][2] + bv.z, acc[i][j][3] + bv.w);
            }
            *(float4*)&C[(size_t)row * D_ + col0] = v;
        }
    }
}
#undef FRAG_T

// ---------------------------------------------------------------------------
// fused_kv (unchanged)
// ---------------------------------------------------------------------------
#define STAGEK_(sub_, bi_) do { \
    const int n0_ = nsp*1024 + (sub_)*128; \
    _Pragma("unroll") \
    for (int it_ = 0; it_ < 2; ++it_) { \
        int idx_ = it_*512 + tid; \
        int row_ = idx_ >> 3, seg_ = (idx_ & 7) ^ (row_ & 7); \
        GLD(Kh + (size_t)(b*N_ + n0_ + row_) * D_ + h*DK_ + seg_*8, \
            &sK[bi_][idx_*8]); \
    } } while (0)

#define STAGEVT_(sub_) do { \
    const int n0_ = nsp*1024 + (sub_)*128; \
    _Pragma("unroll") \
    for (int it_ = 0; it_ < 2; ++it_) { \
        int idx_ = it_*512 + tid; \
        int row_ = idx_ >> 4, seg_ = (idx_ & 15) ^ (row_ & 7); \
        GLD(VT + ((size_t)bh*VTROWS_ + row_)*N_ + n0_ + seg_*8, \
            &sVT[idx_*8]); \
    } \
    if (tid < 256) { \
        int idx_ = 1024 + tid; \
        int row_ = idx_ >> 4, seg_ = (idx_ & 15) ^ (row_ & 7); \
        GLD(VT + ((size_t)bh*VTROWS_ + row_)*N_ + n0_ + seg_*8, \
            &sVT[idx_*8]); \
    } } while (0)

#define STAGEOM_(arr_, src_) do { \
    _Pragma("unroll") \
    for (int q_ = 0; q_ < 4; ++q_) { \
        int idx_ = q_*512 + tid; \
        int row_ = idx_ >> 3, seg_ = (idx_ & 7) ^ (row_ & 7); \
        GLD((src_) + (size_t)row_*DK_ + seg_*8, &(arr_)[idx_*8]); \
    } } while (0)

__global__ __launch_bounds__(512, 1)
void fused_kv(const f16* __restrict__ Kh, const bf16* __restrict__ VT,
              const f16* __restrict__ omhi, const f16* __restrict__ omlo,
              const int* __restrict__ mask, float* __restrict__ KVt32)
{
    __shared__ __align__(16) f16  sK[2][128*64];      // 32 KB, swizzled
    __shared__ __align__(16) bf16 sVT[VTROWS_*128];   // 20 KB single, swizzled
    __shared__ __align__(16) f16  sOmH[M_*DK_];       // 32 KB, swizzled
    __shared__ __align__(16) f16  sOmL[M_*DK_];       // 32 KB, swizzled
    __shared__ __align__(16) bf16 sPhi[M_*PHK_PAD];   // 34 KB  [m][68] n-half
    const int nsp = blockIdx.x;          // 0..3
    const int h = blockIdx.y, b = blockIdx.z;
    const int bh = b*H_ + h;
    const int tid = threadIdx.x, lane = tid & 63, wave = tid >> 6;
    const int m16 = lane & 15, quad = lane >> 4;
    const int wm = wave * 32;            // wave's m-range for kv MFMA
    const int nloc = wave*16 + quad*4;   // wave's n-rows: wave*16..+15
    const float inv_sqrt_m = rsqrtf((float)M_ + 1e-6f);
    const f16* omh = omhi + (size_t)h * M_ * DK_;
    const f16* oml = omlo + (size_t)h * M_ * DK_;

    f32x4 kvacc[5][2];
    #pragma unroll
    for (int d = 0; d < 5; ++d)
        #pragma unroll
        for (int j = 0; j < 2; ++j)
            kvacc[d][j] = (f32x4){0.f, 0.f, 0.f, 0.f};

    STAGEOM_(sOmH, omh);
    STAGEOM_(sOmL, oml);
    STAGEK_(0, 0);

    for (int sub = 0; sub < 8; ++sub) {
        const int cur = sub & 1;
        const int n0 = nsp*1024 + sub*128;

        asm volatile("s_waitcnt vmcnt(0) lgkmcnt(0)");
        SBAR_();
        BAR_();

        int4 mv4 = *(const int4*)&mask[b*N_ + n0 + nloc];
        const int* mv = (const int*)&mv4;
        STAGEVT_(sub);
        if (sub < 7) STAGEK_(sub+1, cur^1);

        const char* kb = (const char*)&sK[cur][0];
        const int rowb = wave*16 + m16;
        f16x8 ah0 = *(const f16x8*)(kb + ((rowb*128 +      quad*16) ^ ((rowb & 7) << 4)));
        f16x8 ah1 = *(const f16x8*)(kb + ((rowb*128 + 64 + quad*16) ^ ((rowb & 7) << 4)));

        f32x4 acc[16];
        #pragma unroll
        for (int j = 0; j < 16; ++j) acc[j] = (f32x4){0.f, 0.f, 0.f, 0.f};

        PRIO1_();
        #pragma unroll
        for (int j = 0; j < 16; ++j) {
            int rowm = j*16 + m16;
            int bo0 = (rowm*128 +      quad*16) ^ ((rowm & 7) << 4);
            int bo1 = (rowm*128 + 64 + quad*16) ^ ((rowm & 7) << 4);
            f16x8 bh0 = *(const f16x8*)((const char*)sOmH + bo0);
            f16x8 bh1 = *(const f16x8*)((const char*)sOmH + bo1);
            f16x8 bl0 = *(const f16x8*)((const char*)sOmL + bo0);
            f16x8 bl1 = *(const f16x8*)((const char*)sOmL + bo1);
            acc[j] = __builtin_amdgcn_mfma_f32_16x16x32_f16(ah0, bh0, acc[j], 0,0,0);
            acc[j] = __builtin_amdgcn_mfma_f32_16x16x32_f16(ah0, bl0, acc[j], 0,0,0);
            acc[j] = __builtin_amdgcn_mfma_f32_16x16x32_f16(ah1, bh1, acc[j], 0,0,0);
            acc[j] = __builtin_amdgcn_mfma_f32_16x16x32_f16(ah1, bl1, acc[j], 0,0,0);
        }
        PRIO0_();

        #pragma unroll
        for (int r = 0; r < 4; ++r) {
            float mx = acc[0][r];
            #pragma unroll
            for (int j = 1; j < 16; ++j) mx = fmaxf(mx, acc[j][r]);
            mx = fmaxf(mx, __shfl_xor(mx, 1, 64));
            mx = fmaxf(mx, __shfl_xor(mx, 2, 64));
            mx = fmaxf(mx, __shfl_xor(mx, 4, 64));
            mx = fmaxf(mx, __shfl_xor(mx, 8, 64));
            #pragma unroll
            for (int j = 0; j < 16; ++j)
                acc[j][r] = __expf(acc[j][r] - mx) * inv_sqrt_m;
        }

        if (wave < 4) {
            #pragma unroll
            for (int j = 0; j < 16; ++j) {
                bf16x4 pk;
                #pragma unroll
                for (int r = 0; r < 4; ++r)
                    pk[r] = mv[r] ? (bf16)0.0f : (bf16)acc[j][r];
                *(bf16x4*)&sPhi[(j*16 + m16)*PHK_PAD + nloc] = pk;
            }
        }
        asm volatile("s_waitcnt lgkmcnt(0)");
        if (sub < 7) { asm volatile("s_waitcnt vmcnt(2)"); }
        else         { asm volatile("s_waitcnt vmcnt(0)"); }
        SBAR_();
        BAR_();   // (C1) PhiA + VT visible

        PRIO1_();
        #pragma unroll
        for (int ks = 0; ks < 2; ++ks) {
            bf16x8 av[5], bp[2];
            #pragma unroll
            for (int d = 0; d < 5; ++d) {
                int rowv = d*16 + m16;
                av[d] = *(const bf16x8*)((const char*)sVT +
                        ((rowv*256 + ks*64 + quad*16) ^ ((rowv & 7) << 4)));
            }
            #pragma unroll
            for (int j = 0; j < 2; ++j)
                bp[j] = *(const bf16x8*)&sPhi[(wm + j*16 + m16)*PHK_PAD + ks*32 + quad*8];
            #pragma unroll
            for (int d = 0; d < 5; ++d)
                #pragma unroll
                for (int j = 0; j < 2; ++j)
                    kvacc[d][j] = __builtin_amdgcn_mfma_f32_16x16x32_bf16(
                        av[d], bp[j], kvacc[d][j], 0, 0, 0);
        }
        PRIO0_();
        asm volatile("s_waitcnt lgkmcnt(0)");
        SBAR_();
        BAR_();   // (C2)

        if (wave >= 4) {
            #pragma unroll
            for (int j = 0; j < 16; ++j) {
                bf16x4 pk;
                #pragma unroll
                for (int r = 0; r < 4; ++r)
                    pk[r] = mv[r] ? (bf16)0.0f : (bf16)acc[j][r];
                *(bf16x4*)&sPhi[(j*16 + m16)*PHK_PAD + (nloc - 64)] = pk;
            }
        }
        asm volatile("s_waitcnt lgkmcnt(0)");
        SBAR_();
        BAR_();   // (C3)

        PRIO1_();
        #pragma unroll
        for (int ks = 0; ks < 2; ++ks) {
            bf16x8 av[5], bp[2];
            #pragma unroll
            for (int d = 0; d < 5; ++d) {
                int rowv = d*16 + m16;
                av[d] = *(const bf16x8*)((const char*)sVT +
                        ((rowv*256 + 128 + ks*64 + quad*16) ^ ((rowv & 7) << 4)));
            }
            #pragma unroll
            for (int j = 0; j < 2; ++j)
                bp[j] = *(const bf16x8*)&sPhi[(wm + j*16 + m16)*PHK_PAD + ks*32 + quad*8];
            #pragma unroll
            for (int d = 0; d < 5; ++d)
                #pragma unroll
                for (int j = 0; j < 2; ++j)
                    kvacc[d][j] = __builtin_amdgcn_mfma_f32_16x16x32_bf16(
                        av[d], bp[j], kvacc[d][j], 0, 0, 0);
        }
        PRIO0_();
    }

    #pragma unroll
    for (int d = 0; d < 5; ++d)
        #pragma unroll
        for (int j = 0; j < 2; ++j) {
            int drow = d*16 + quad*4;
            int m = wm + j*16 + m16;
            #pragma unroll
            for (int r = 0; r < 4; ++r)
                atomicAdd(&KVt32[((size_t)bh*VTROWS_ + drow + r)*M_ + m],
                          kvacc[d][j][r]);
        }
}

// ---------------------------------------------------------------------------
// fused_ctx v3: (1) SWAPPED feat mfma(om, q) -> lane holds m=j*16+quad*4+r,
// n=wave*16+m16: Phi writes become bf16x4 along m (4x fewer LDS stores) and
// softmax cross-lane reduce shrinks to 2 shfls (xor 16,32). Bit-identical
// math (exact transpose; fmax/exp order-independent). (2) KVb fragments
// hoisted out of the nb loop (loop-invariant). (3) Q reg-prefetch ping-pong:
// nb+1's two f16x8 loads issued right after feat, land under softmax+GEMM.
// ---------------------------------------------------------------------------
__global__ __launch_bounds__(512, 1)
void fused_ctx(const f16* __restrict__ Qh, const f16* __restrict__ omhi,
               const f16* __restrict__ omlo, const bf16* __restrict__ KVb,
               bf16* __restrict__ ctx)
{
    __shared__ __align__(16) f16  sOmH[M_*DK_];        // 32 KB, swizzled
    __shared__ __align__(16) f16  sOmL[M_*DK_];        // 32 KB, swizzled
    __shared__ __align__(16) bf16 sPhi[128*PHQ_PAD];   // 66 KB [n][264]
    __shared__ float sden[2][128];
    const int nsp = blockIdx.x;          // 0..3
    const int h = blockIdx.y, b = blockIdx.z;
    const int bh = b*H_ + h;
    const int tid = threadIdx.x, lane = tid & 63, wave = tid >> 6;
    const int m16 = lane & 15, quad = lane >> 4;
    const float inv_sqrt_m = rsqrtf((float)M_ + 1e-6f);
    const f16* omh = omhi + (size_t)h * M_ * DK_;
    const f16* oml = omlo + (size_t)h * M_ * DK_;

    STAGEOM_(sOmH, omh);
    STAGEOM_(sOmL, oml);

    const int wq = wave >> 2;            // GEMM q-half
    const int wc = wave & 3;             // GEMM col quarter (32 cols)

    // hoisted KVb fragments (loop-invariant across nb); overlap with om wait
    bf16x8 wf[2][8];
    #pragma unroll
    for (int jr = 0; jr < 2; ++jr) {
        int rowk = wc*32 + jr*16 + m16;
        #pragma unroll
        for (int ks = 0; ks < 8; ++ks)
            wf[jr][ks] = *(const bf16x8*)&KVb[((size_t)bh*KVROWS_ + rowk)*M_
                                              + ks*32 + quad*8];
    }

    // prefetch Q for nb=0
    const int rowq = wave*16 + m16;
    const f16* qbase = Qh + (size_t)(b*N_ + nsp*1024 + rowq)*D_ + h*DK_;
    f16x8 qa0 = *(const f16x8*)(qbase + quad*8);
    f16x8 qa1 = *(const f16x8*)(qbase + 32 + quad*8);

    asm volatile("s_waitcnt vmcnt(0)");  // om (+wf, +q) landed
    SBAR_();
    BAR_();

    for (int nb = 0; nb < 8; ++nb) {
        const int q0 = nsp*1024 + nb*128;

        // ---- feat, swapped: A=om (rows m), B=q (cols n) ----
        f32x4 acc[16];
        #pragma unroll
        for (int j = 0; j < 16; ++j) acc[j] = (f32x4){0.f, 0.f, 0.f, 0.f};

        PRIO1_();
        #pragma unroll
        for (int j = 0; j < 16; ++j) {
            int rowm = j*16 + m16;
            int bo0 = (rowm*128 +      quad*16) ^ ((rowm & 7) << 4);
            int bo1 = (rowm*128 + 64 + quad*16) ^ ((rowm & 7) << 4);
            f16x8 bh0 = *(const f16x8*)((const char*)sOmH + bo0);
            f16x8 bh1 = *(const f16x8*)((const char*)sOmH + bo1);
            f16x8 bl0 = *(const f16x8*)((const char*)sOmL + bo0);
            f16x8 bl1 = *(const f16x8*)((const char*)sOmL + bo1);
            acc[j] = __builtin_amdgcn_mfma_f32_16x16x32_f16(bh0, qa0, acc[j], 0,0,0);
            acc[j] = __builtin_amdgcn_mfma_f32_16x16x32_f16(bl0, qa0, acc[j], 0,0,0);
            acc[j] = __builtin_amdgcn_mfma_f32_16x16x32_f16(bh1, qa1, acc[j], 0,0,0);
            acc[j] = __builtin_amdgcn_mfma_f32_16x16x32_f16(bl1, qa1, acc[j], 0,0,0);
        }
        PRIO0_();

        // prefetch next nb's Q (lands under softmax + GEMM)
        f16x8 qn0, qn1;
        if (nb < 7) {
            const f16* qb2 = qbase + (size_t)(nb+1)*128*D_;
            qn0 = *(const f16x8*)(qb2 + quad*8);
            qn1 = *(const f16x8*)(qb2 + 32 + quad*8);
        }

        // ---- softmax over m: within-lane (j,r) then cross-quad shfls ----
        {
            float mx = acc[0][0];
            #pragma unroll
            for (int j = 0; j < 16; ++j)
                #pragma unroll
                for (int r = 0; r < 4; ++r)
                    mx = fmaxf(mx, acc[j][r]);
            mx = fmaxf(mx, __shfl_xor(mx, 16, 64));
            mx = fmaxf(mx, __shfl_xor(mx, 32, 64));
            #pragma unroll
            for (int j = 0; j < 16; ++j)
                #pragma unroll
                for (int r = 0; r < 4; ++r)
                    acc[j][r] = __expf(acc[j][r] - mx) * inv_sqrt_m;
        }

        // ---- Phi -> sPhi [n][m], vectorized bf16x4 along m ----
        {
            const int nrow = wave*16 + m16;
            #pragma unroll
            for (int j = 0; j < 16; ++j) {
                bf16x4 pk = { (bf16)acc[j][0], (bf16)acc[j][1],
                              (bf16)acc[j][2], (bf16)acc[j][3] };
                *(bf16x4*)&sPhi[nrow*PHQ_PAD + j*16 + quad*4] = pk;
            }
        }
        asm volatile("s_waitcnt lgkmcnt(0)");
        SBAR_();
        BAR_();   // Phi visible

        // ---- ctx GEMM: C[128 q][128 kvrows], waves 2x4 ----
        f32x4 cacc[4][2];
        #pragma unroll
        for (int i = 0; i < 4; ++i)
            #pragma unroll
            for (int j = 0; j < 2; ++j)
                cacc[i][j] = (f32x4){0.f, 0.f, 0.f, 0.f};

        PRIO1_();
        #pragma unroll
        for (int ks = 0; ks < 8; ++ks) {
            bf16x8 af[4];
            #pragma unroll
            for (int i = 0; i < 4; ++i)
                af[i] = *(const bf16x8*)&sPhi[(wq*64 + i*16 + m16)*PHQ_PAD
                                              + ks*32 + quad*8];
            #pragma unroll
            for (int i = 0; i < 4; ++i)
                #pragma unroll
                for (int jr = 0; jr < 2; ++jr)
                    cacc[i][jr] = __builtin_amdgcn_mfma_f32_16x16x32_bf16(
                        af[i], wf[jr][ks], cacc[i][jr], 0, 0, 0);
        }
        PRIO0_();

        // den = cols 64 (ksum_hi) + 65 (ksum_lo): owned by wc==2, jr==0
        if (wc == 2 && m16 < 2) {
            #pragma unroll
            for (int i = 0; i < 4; ++i)
                #pragma unroll
                for (int r = 0; r < 4; ++r)
                    sden[m16][wq*64 + i*16 + quad*4 + r] = cacc[i][0][r];
        }
        asm volatile("s_waitcnt lgkmcnt(0)");
        SBAR_();
        BAR_();   // sden visible

        if (wc < 2) {
            #pragma unroll
            for (int i = 0; i < 4; ++i) {
                #pragma unroll
                for (int r = 0; r < 4; ++r) {
                    int lrow = wq*64 + i*16 + quad*4 + r;
                    float den = sden[0][lrow] + sden[1][lrow] + EPS_;
                    #pragma unroll
                    for (int jr = 0; jr < 2; ++jr)
                        ctx[(size_t)(b*N_ + q0 + lrow)*D_ + h*DK_
                            + wc*32 + jr*16 + m16] = (bf16)(cacc[i][jr][r] / den);
                }
            }
        }
        asm volatile("s_waitcnt lgkmcnt(0)");
        SBAR_();
        BAR_();   // sPhi/sden free for next nb

        if (nb < 7) { qa0 = qn0; qa1 = qn1; }
    }
}

// ---------------------------------------------------------------------------
extern "C" void kernel_launch(void* const* d_in, const int* in_sizes, int n_in,
                              void* d_out, int out_size, void* d_ws, size_t ws_size,
                              hipStream_t stream)
{
    const float* x     = (const float*)d_in[0];
    const int*   mask  = (const int*)d_in[1];     // 1 = PAD
    const float* Wqkv  = (const float*)d_in[2];
    const float* bqkv  = (const float*)d_in[3];
    const float* Wout  = (const float*)d_in[4];
    const float* bout  = (const float*)d_in[5];
    const float* omega = (const float*)d_in[6];
    float* out = (float*)d_out;

    char* w = (char*)d_ws;
    f16*   Wh    = (f16*)w;    w += (size_t)3*D_*D_ * 2;              //   6.29 MB
    bf16*  Wob   = (bf16*)w;   w += (size_t)D_*D_ * 2;                //   2.10 MB
    f16*   omhi  = (f16*)w;    w += (size_t)H_*M_*DK_ * 2;            //   0.52 MB
    f16*   omlo  = (f16*)w;    w += (size_t)H_*M_*DK_ * 2;            //   0.52 MB
    f16*   xh    = (f16*)w;    w += (size_t)R_ * D_ * 2;              //  33.55 MB
    f16*   Qh    = (f16*)w;    w += (size_t)R_ * D_ * 2;              //  33.55 MB
    f16*   Kh    = (f16*)w;    w += (size_t)R_ * D_ * 2;              //  33.55 MB (-> ctx)
    bf16*  VT    = (bf16*)w;   w += (size_t)B_*H_*VTROWS_*N_ * 2;     //  41.94 MB
    float* KVt32 = (float*)w;  w += (size_t)B_*H_*VTROWS_*M_ * 4;     //   5.24 MB
    bf16*  KVb   = (bf16*)w;   w += (size_t)B_*H_*KVROWS_*M_ * 2;     //   4.19 MB
    bf16*  VC    = (bf16*)Kh;                                         // alias (Kh dead after fused_kv)

    // 0) all prep in one launch
    prep_all<<<24064, 256, 0, stream>>>(x, xh, Wqkv, Wh, omega, omhi, omlo,
                                        Wout, Wob, KVt32, VT);

    // 1) unified QKV projection, one launch: Q/K swapped-epilogue + V -> VT
    gemm_qkv_all<<<dim3(12, R_/256), 512, 0, stream>>>(xh, Wh, bqkv, Qh, Kh, VT);

    // 2) fused K-features + KV/ksum accumulation (Phi_K in LDS only)
    fused_kv<<<dim3(4, H_, B_), 512, 0, stream>>>(Kh, VT, omhi, omlo, mask, KVt32);

    // 3) pack KVt32 -> KVb bf16 (ksum hi/lo rows 64/65, zero pad to 128)
    pack_kv<<<(B_*H_*KVROWS_*M_ + 255)/256, 256, 0, stream>>>(KVt32, KVb);

    // 4) fused Q-features + ctx (Phi_Q in LDS only) -> VC bf16 (aliases Kh)
    fused_ctx<<<dim3(4, H_, B_), 512, 0, stream>>>(Qh, omhi, omlo, KVb, VC);

    // 5) output projection + bias + PAD-query zeroing -> fp32 out (8-phase)
    gemm_out8<<<dim3(4, R_/256), 512, 0, stream>>>(VC, Wob, bout, out, mask);
}